// Round 2
// baseline (277.829 us; speedup 1.0000x reference)
//
#include <hip/hip_runtime.h>
#include <hip/hip_bf16.h>

// MoE fused block, MI355X gfx950.
// Shapes: B=2, C=256, T*H*W=16384, E=4, K=2. All inputs fp32, output fp32.
// Strategy: prepack w1/w2 into bf16 MFMA-B-fragment-major layout in d_ws,
// then one fused kernel: gate (fp64 logits -> top-2 softmax) -> per-expert
// GEMM1(+bias,SiLU, pre-scale by gate weight) -> GEMM2 accumulated over all
// experts (K=1024 concat) -> +combined b2 bias + fp32 residual.
//
// R1 post-mortem: absmax 0.1445 came from top-k tie flips (gate logits were
// computed from the bf16 LDS copy of x, perturbing ~0.3% of positions across
// the |l2-l3| tie boundary). Gate now reads fp32 x and accumulates in fp64.

#define C_DIM 256
#define S_DIM 16384          // T*H*W
#define E_DIM 4
#define MT 64                // positions per workgroup
#define XST 264              // Xs row stride in bf16 (pad: 4-bank shift/row)
#define WFRAG_ELEMS 262144   // elements per prepacked weight tensor (4*16*8*64*8)

typedef __attribute__((ext_vector_type(8))) short bf16x8;
typedef __attribute__((ext_vector_type(4))) float f32x4;

// Prepack: dst[(half,e,nt,kc,lane,j)] = src[(e*256 + nt*16 + (lane&15))*256
//                                           + kc*32 + (lane>>4)*8 + j]
// i.e. B-operand fragment layout for mfma_f32_16x16x32_bf16:
//   n = lane&15 (output channel within 16-tile), k = quad*8 + j.
__global__ __launch_bounds__(256) void prepack_kernel(
    const float* __restrict__ w1, const float* __restrict__ w2,
    __hip_bfloat16* __restrict__ dst)
{
  int o = blockIdx.x * 256 + threadIdx.x;   // 0 .. 524287
  int half = o >> 18;                       // 0: w1, 1: w2
  int idx = o & (WFRAG_ELEMS - 1);
  int j    = idx & 7;
  int lane = (idx >> 3) & 63;
  int kc   = (idx >> 9) & 7;
  int nt   = (idx >> 12) & 15;
  int e    = (idx >> 16) & 3;
  const float* src = half ? w2 : w1;
  int si = (e*256 + nt*16 + (lane & 15))*256 + kc*32 + (lane >> 4)*8 + j;
  dst[o] = __float2bfloat16(src[si]);
}

__global__ __launch_bounds__(256, 2) void moe_fused_kernel(
    const float* __restrict__ x,
    const float* __restrict__ gate_w,
    const float* __restrict__ gate_b,
    const float* __restrict__ b1,
    const float* __restrict__ b2,
    const __hip_bfloat16* __restrict__ wp,   // [W1P | W2P] prepacked bf16
    float* __restrict__ out)
{
  // LDS: 33792 + 16384 + 1024 = 51200 B -> fits well under 64 KB
  __shared__ __align__(16) __hip_bfloat16 Xs[MT * XST];   // X tile, row-major padded
  __shared__ __align__(16) short HsS[4 * 4 * 64 * 8];     // per-wave H fragments
  __shared__ float Wgt[MT * 4];                           // logits -> gate weights

  const int tid  = threadIdx.x;
  const int lane = tid & 63;
  const int wv   = tid >> 6;     // wave 0..3, owns positions [wv*16, wv*16+16)
  const int r    = lane & 15;
  const int q    = lane >> 4;

  const int g  = blockIdx.x;
  const int b  = g >> 8;                 // 256 workgroups per batch
  const int s0 = (g & 255) * MT;
  const float* xb = x + (size_t)b * C_DIM * S_DIM + s0;

  // ---- stage X tile into LDS as bf16 (coalesced float4 over positions) ----
  {
    const int p4 = (tid & 15) * 4;
    const int c0 = tid >> 4;
#pragma unroll
    for (int cc = 0; cc < 16; ++cc) {
      const int c = cc * 16 + c0;
      const float4 v = *(const float4*)(xb + (size_t)c * S_DIM + p4);
      Xs[(p4+0)*XST + c] = __float2bfloat16(v.x);
      Xs[(p4+1)*XST + c] = __float2bfloat16(v.y);
      Xs[(p4+2)*XST + c] = __float2bfloat16(v.z);
      Xs[(p4+3)*XST + c] = __float2bfloat16(v.w);
    }
  }

  // ---- gate logits in fp64 from ORIGINAL fp32 x (tie-flip-proof) ----
  // wave e computes all 64 positions' logit for expert e; coalesced over p.
  {
    const int p = lane;          // 0..63
    const int e = wv;            // 0..3 (wave-uniform -> gw loads are scalar)
    double acc = (double)gate_b[e];
    const float* gw = gate_w + e * C_DIM;
    const float* xr = xb + p;
    for (int c = 0; c < C_DIM; ++c)
      acc += (double)xr[(size_t)c * S_DIM] * (double)gw[c];
    Wgt[p*4 + e] = (float)acc;
  }
  __syncthreads();   // Xs staged AND all logits written

  // ---- top-2 + softmax per position (first-index-wins on ties, like top_k) ----
  if (tid < MT) {
    const int p = tid;
    const float l0 = Wgt[p*4+0], l1 = Wgt[p*4+1], l2 = Wgt[p*4+2], l3 = Wgt[p*4+3];
    int i1 = 0; float v1 = l0;
    if (l1 > v1) { v1 = l1; i1 = 1; }
    if (l2 > v1) { v1 = l2; i1 = 2; }
    if (l3 > v1) { v1 = l3; i1 = 3; }
    float v2 = -3.0e38f; int i2 = 0;
    if (i1 != 0 && l0 > v2) { v2 = l0; i2 = 0; }
    if (i1 != 1 && l1 > v2) { v2 = l1; i2 = 1; }
    if (i1 != 2 && l2 > v2) { v2 = l2; i2 = 2; }
    if (i1 != 3 && l3 > v2) { v2 = l3; i2 = 3; }
    const float wA = 1.0f / (1.0f + __expf(v2 - v1));   // softmax of {v1,v2}
    const float wB = 1.0f - wA;
    Wgt[p*4+0] = (i1 == 0) ? wA : ((i2 == 0) ? wB : 0.0f);
    Wgt[p*4+1] = (i1 == 1) ? wA : ((i2 == 1) ? wB : 0.0f);
    Wgt[p*4+2] = (i1 == 2) ? wA : ((i2 == 2) ? wB : 0.0f);
    Wgt[p*4+3] = (i1 == 3) ? wA : ((i2 == 3) ? wB : 0.0f);
  }

  // ---- X A-fragments for this wave's 16 rows, all K=256: 32 VGPRs ----
  // A layout: m = lane&15 -> position wv*16+r ; k = q*8 + j within 32-chunk.
  bf16x8 xfrag[8];
  const short* XsS = (const short*)Xs;
#pragma unroll
  for (int kc = 0; kc < 8; ++kc)
    xfrag[kc] = *(const bf16x8*)(XsS + (wv*16 + r)*XST + kc*32 + q*8);

  __syncthreads();   // Wgt final; expert loop below needs no further barriers

  f32x4 oacc[16];
#pragma unroll
  for (int i = 0; i < 16; ++i) oacc[i] = (f32x4){0.f, 0.f, 0.f, 0.f};

  const short* W1P = (const short*)wp;
  const short* W2P = (const short*)wp + WFRAG_ELEMS;

  for (int e = 0; e < E_DIM; ++e) {
    float wreg[4];
#pragma unroll
    for (int reg = 0; reg < 4; ++reg)
      wreg[reg] = Wgt[(wv*16 + q*4 + reg)*4 + e];

    for (int half = 0; half < 2; ++half) {
      // ---- GEMM1: H[p][n], n in [half*128, half*128+128), K=256 ----
      for (int nt1 = 0; nt1 < 8; ++nt1) {
        const int nt = half*8 + nt1;
        f32x4 hacc = (f32x4){0.f, 0.f, 0.f, 0.f};
        const short* bp = W1P + ((e*16 + nt)*8)*512 + lane*8;
#pragma unroll
        for (int kc = 0; kc < 8; ++kc) {
          const bf16x8 bf = *(const bf16x8*)(bp + kc*512);
          hacc = __builtin_amdgcn_mfma_f32_16x16x32_bf16(xfrag[kc], bf, hacc, 0, 0, 0);
        }
        // epilogue: +b1, SiLU, pre-scale by gate weight, write to per-wave Hs
        // C/D layout: row(p-offset) = q*4+reg, col(n-offset) = r.
        const int n0 = nt*16 + r;
        const float bias = b1[e*256 + n0];
        const int nl = nt1*16 + r;   // n local to this half, 0..127
        const int hbase = ((wv*4 + (nl >> 5))*64 + ((nl >> 3) & 3)*16 + q*4)*8 + (nl & 7);
#pragma unroll
        for (int reg = 0; reg < 4; ++reg) {
          const float z = hacc[reg] + bias;
          const float h = z / (1.0f + __expf(-z)) * wreg[reg];
          __hip_bfloat16 hb = __float2bfloat16(h);
          HsS[hbase + reg*8] = *(short*)&hb;
        }
      }
      // ---- GEMM2 partial: oacc += H_half @ W2_e^T (K-chunk = this half) ----
      // Hs rows are wave-private (this wave wrote exactly the rows it reads),
      // so no __syncthreads needed; compiler inserts lgkmcnt waits.
      bf16x8 hfrag[4];
#pragma unroll
      for (int kk = 0; kk < 4; ++kk)
        hfrag[kk] = *(const bf16x8*)((const short*)HsS + ((wv*4 + kk)*64 + lane)*8);
#pragma unroll
      for (int nt2 = 0; nt2 < 16; ++nt2) {
        const short* bp2 = W2P + ((e*16 + nt2)*8 + half*4)*512 + lane*8;
        f32x4 a = oacc[nt2];
#pragma unroll
        for (int kk = 0; kk < 4; ++kk) {
          const bf16x8 bf = *(const bf16x8*)(bp2 + kk*512);
          a = __builtin_amdgcn_mfma_f32_16x16x32_bf16(hfrag[kk], bf, a, 0, 0, 0);
        }
        oacc[nt2] = a;
      }
    }
  }

  // ---- epilogue: out = oacc + sum_e w[p,e]*b2[e,c] + x (fp32 residual) ----
  float wv4[4][4];
#pragma unroll
  for (int reg = 0; reg < 4; ++reg)
#pragma unroll
    for (int e = 0; e < 4; ++e)
      wv4[reg][e] = Wgt[(wv*16 + q*4 + reg)*4 + e];

  float* ob = out + (size_t)b * C_DIM * S_DIM + s0;
#pragma unroll
  for (int nt = 0; nt < 16; ++nt) {
    const int c = nt*16 + r;
    const float b20 = b2[c], b21 = b2[256 + c], b22 = b2[512 + c], b23 = b2[768 + c];
    float* op = ob + (size_t)c * S_DIM;
    const float* xp = xb + (size_t)c * S_DIM;
#pragma unroll
    for (int reg = 0; reg < 4; ++reg) {
      const int p = wv*16 + q*4 + reg;
      const float wsum = wv4[reg][0]*b20 + wv4[reg][1]*b21
                       + wv4[reg][2]*b22 + wv4[reg][3]*b23;
      op[p] = oacc[nt][reg] + wsum + xp[p];
    }
  }
}

extern "C" void kernel_launch(void* const* d_in, const int* in_sizes, int n_in,
                              void* d_out, int out_size, void* d_ws, size_t ws_size,
                              hipStream_t stream)
{
  (void)in_sizes; (void)n_in; (void)out_size; (void)ws_size;
  const float* x      = (const float*)d_in[0];
  const float* gate_w = (const float*)d_in[1];
  const float* gate_b = (const float*)d_in[2];
  const float* w1     = (const float*)d_in[3];
  const float* b1     = (const float*)d_in[4];
  const float* w2     = (const float*)d_in[5];
  const float* b2     = (const float*)d_in[6];
  float* out = (float*)d_out;
  __hip_bfloat16* wpack = (__hip_bfloat16*)d_ws;   // needs 1 MiB of scratch

  // Prepack runs every launch (ws is re-poisoned before every timed call).
  prepack_kernel<<<2048, 256, 0, stream>>>(w1, w2, wpack);
  moe_fused_kernel<<<512, 256, 0, stream>>>(x, gate_w, gate_b, b1, b2, wpack, out);
}

// Round 3
// 149.460 us; speedup vs baseline: 1.8589x; 1.8589x over previous
//
#include <hip/hip_runtime.h>
#include <hip/hip_bf16.h>

// MoE fused block, MI355X gfx950.
// Shapes: B=2, C=256, T*H*W=16384, E=4, K=2. All inputs fp32, output fp32.
//
// R2 -> R3: waves now split the N dimension (each wave owns a 64-wide output
// slice, all 64 positions) so every global B-fragment load is reused by 4
// MFMAs (4 M-tiles), cutting per-WG weight traffic 4x (4MB -> 1MB) and the
// latency-exposed load:MFMA ratio from 1:1 to 1:4. H round-trips through a
// shared LDS tile (2 barriers per expert). Explicit 1-deep prefetch of the
// next kc's B fragments.

#define C_DIM 256
#define S_DIM 16384          // T*H*W
#define E_DIM 4
#define MT 64                // positions per workgroup
#define XST 264              // LDS row stride in shorts (pad vs 256)
#define WFRAG_ELEMS 262144   // elements per prepacked weight tensor (4*16*8*64*8)

typedef __attribute__((ext_vector_type(8))) short bf16x8;
typedef __attribute__((ext_vector_type(4))) float f32x4;

// Prepack: dst[(half,e,nt,kc,lane,j)] = src[(e*256 + nt*16 + (lane&15))*256
//                                           + kc*32 + (lane>>4)*8 + j]
// B-operand fragment layout for mfma_f32_16x16x32_bf16:
//   n = lane&15, k = (lane>>4)*8 + j.
__global__ __launch_bounds__(256) void prepack_kernel(
    const float* __restrict__ w1, const float* __restrict__ w2,
    __hip_bfloat16* __restrict__ dst)
{
  int o = blockIdx.x * 256 + threadIdx.x;   // 0 .. 524287
  int half = o >> 18;                       // 0: w1, 1: w2
  int idx = o & (WFRAG_ELEMS - 1);
  int j    = idx & 7;
  int lane = (idx >> 3) & 63;
  int kc   = (idx >> 9) & 7;
  int nt   = (idx >> 12) & 15;
  int e    = (idx >> 16) & 3;
  const float* src = half ? w2 : w1;
  int si = (e*256 + nt*16 + (lane & 15))*256 + kc*32 + (lane >> 4)*8 + j;
  dst[o] = __float2bfloat16(src[si]);
}

__global__ __launch_bounds__(256, 2) void moe_fused_kernel(
    const float* __restrict__ x,
    const float* __restrict__ gate_w,
    const float* __restrict__ gate_b,
    const float* __restrict__ b1,
    const float* __restrict__ b2,
    const __hip_bfloat16* __restrict__ wp,   // [W1P | W2P] prepacked bf16
    float* __restrict__ out)
{
  // LDS: 33792 + 33792 + 1024 = 68608 B -> 2 blocks/CU (160 KiB budget)
  __shared__ __align__(16) __hip_bfloat16 Xs[MT * XST];   // X tile [pos][ch]
  __shared__ __align__(16) __hip_bfloat16 Hs[MT * XST];   // H tile [pos][n] (per expert)
  __shared__ float Wgt[MT * 4];                           // gate weights

  const int tid  = threadIdx.x;
  const int lane = tid & 63;
  const int wv   = tid >> 6;     // wave 0..3: owns output n-slice [wv*64, wv*64+64)
  const int r    = lane & 15;
  const int q    = lane >> 4;

  const int g  = blockIdx.x;
  const int b  = g >> 8;                 // 256 workgroups per batch
  const int s0 = (g & 255) * MT;
  const float* xb = x + (size_t)b * C_DIM * S_DIM + s0;

  // ---- stage X tile into LDS as bf16 (coalesced float4 over positions) ----
  {
    const int p4 = (tid & 15) * 4;
    const int c0 = tid >> 4;
#pragma unroll
    for (int cc = 0; cc < 16; ++cc) {
      const int c = cc * 16 + c0;
      const float4 v = *(const float4*)(xb + (size_t)c * S_DIM + p4);
      Xs[(p4+0)*XST + c] = __float2bfloat16(v.x);
      Xs[(p4+1)*XST + c] = __float2bfloat16(v.y);
      Xs[(p4+2)*XST + c] = __float2bfloat16(v.z);
      Xs[(p4+3)*XST + c] = __float2bfloat16(v.w);
    }
  }

  // ---- gate logits in fp64 from ORIGINAL fp32 x (tie-flip-proof) ----
  // wave e computes all 64 positions' logit for expert e; 4 indep fp64 chains.
  {
    const int p = lane;
    const int e = wv;
    const float* gw = gate_w + e * C_DIM;
    const float* xr = xb + p;
    double a0 = 0.0, a1 = 0.0, a2 = 0.0, a3 = 0.0;
#pragma unroll 4
    for (int c = 0; c < C_DIM; c += 4) {
      a0 += (double)xr[(size_t)(c+0) * S_DIM] * (double)gw[c+0];
      a1 += (double)xr[(size_t)(c+1) * S_DIM] * (double)gw[c+1];
      a2 += (double)xr[(size_t)(c+2) * S_DIM] * (double)gw[c+2];
      a3 += (double)xr[(size_t)(c+3) * S_DIM] * (double)gw[c+3];
    }
    Wgt[p*4 + e] = (float)(((a0 + a1) + (a2 + a3)) + (double)gate_b[e]);
  }
  __syncthreads();   // Xs staged AND all logits written

  // ---- top-2 + softmax per position (first-index-wins, like top_k) ----
  if (tid < MT) {
    const int p = tid;
    const float l0 = Wgt[p*4+0], l1 = Wgt[p*4+1], l2 = Wgt[p*4+2], l3 = Wgt[p*4+3];
    int i1 = 0; float v1 = l0;
    if (l1 > v1) { v1 = l1; i1 = 1; }
    if (l2 > v1) { v1 = l2; i1 = 2; }
    if (l3 > v1) { v1 = l3; i1 = 3; }
    float v2 = -3.0e38f; int i2 = 0;
    if (i1 != 0 && l0 > v2) { v2 = l0; i2 = 0; }
    if (i1 != 1 && l1 > v2) { v2 = l1; i2 = 1; }
    if (i1 != 2 && l2 > v2) { v2 = l2; i2 = 2; }
    if (i1 != 3 && l3 > v2) { v2 = l3; i2 = 3; }
    const float wA = 1.0f / (1.0f + __expf(v2 - v1));   // softmax of {v1,v2}
    const float wB = 1.0f - wA;
    Wgt[p*4+0] = (i1 == 0) ? wA : ((i2 == 0) ? wB : 0.0f);
    Wgt[p*4+1] = (i1 == 1) ? wA : ((i2 == 1) ? wB : 0.0f);
    Wgt[p*4+2] = (i1 == 2) ? wA : ((i2 == 2) ? wB : 0.0f);
    Wgt[p*4+3] = (i1 == 3) ? wA : ((i2 == 3) ? wB : 0.0f);
  }
  __syncthreads();   // Wgt final

  const short* XsS = (const short*)Xs;
  short*       HsW = (short*)Hs;
  const short* HsR = (const short*)Hs;
  const short* W1P = (const short*)wp;
  const short* W2P = (const short*)wp + WFRAG_ELEMS;

  f32x4 oacc[4][4];   // [Mt][t]: persistent out accumulator, K=1024 concat
#pragma unroll
  for (int i = 0; i < 4; ++i)
#pragma unroll
    for (int j = 0; j < 4; ++j) oacc[i][j] = (f32x4){0.f, 0.f, 0.f, 0.f};

  for (int e = 0; e < E_DIM; ++e) {
    // ---- GEMM1: hacc[Mt][t] = X(64x256) @ W1_e^T slice (n in wave's 64) ----
    f32x4 hacc[4][4];
#pragma unroll
    for (int i = 0; i < 4; ++i)
#pragma unroll
      for (int j = 0; j < 4; ++j) hacc[i][j] = (f32x4){0.f, 0.f, 0.f, 0.f};

    {
      const short* w1e = W1P + ((e*16 + wv*4)*8)*512 + lane*8;
      bf16x8 bw[4], bwn[4];
#pragma unroll
      for (int t = 0; t < 4; ++t)
        bw[t] = *(const bf16x8*)(w1e + (t*8 + 0)*512);
#pragma unroll
      for (int kc = 0; kc < 8; ++kc) {
        if (kc < 7) {
#pragma unroll
          for (int t = 0; t < 4; ++t)
            bwn[t] = *(const bf16x8*)(w1e + (t*8 + kc + 1)*512);
        }
        bf16x8 a[4];
#pragma unroll
        for (int Mt = 0; Mt < 4; ++Mt)
          a[Mt] = *(const bf16x8*)(XsS + (Mt*16 + r)*XST + kc*32 + q*8);
#pragma unroll
        for (int Mt = 0; Mt < 4; ++Mt)
#pragma unroll
          for (int t = 0; t < 4; ++t)
            hacc[Mt][t] = __builtin_amdgcn_mfma_f32_16x16x32_bf16(a[Mt], bw[t], hacc[Mt][t], 0, 0, 0);
#pragma unroll
        for (int t = 0; t < 4; ++t) bw[t] = bwn[t];
      }
    }

    // ---- H epilogue: +b1, SiLU, pre-scale by gate weight, write Hs ----
    {
      float wreg[4][4];
#pragma unroll
      for (int Mt = 0; Mt < 4; ++Mt)
#pragma unroll
        for (int reg = 0; reg < 4; ++reg)
          wreg[Mt][reg] = Wgt[(Mt*16 + q*4 + reg)*4 + e];
#pragma unroll
      for (int t = 0; t < 4; ++t) {
        const int n = wv*64 + t*16 + r;
        const float bias = b1[e*256 + n];
#pragma unroll
        for (int Mt = 0; Mt < 4; ++Mt)
#pragma unroll
          for (int reg = 0; reg < 4; ++reg) {
            const float z = hacc[Mt][t][reg] + bias;
            const float h = z / (1.0f + __expf(-z)) * wreg[Mt][reg];
            __hip_bfloat16 hb = __float2bfloat16(h);
            HsW[(Mt*16 + q*4 + reg)*XST + n] = *(short*)&hb;
          }
      }
    }
    __syncthreads();   // Hs complete (all waves' n-slices)

    // ---- GEMM2: oacc += H_e(64x256) @ W2_e^T slice (n in wave's 64) ----
    {
      const short* w2e = W2P + ((e*16 + wv*4)*8)*512 + lane*8;
      bf16x8 bw[4], bwn[4];
#pragma unroll
      for (int t = 0; t < 4; ++t)
        bw[t] = *(const bf16x8*)(w2e + (t*8 + 0)*512);
#pragma unroll
      for (int kc = 0; kc < 8; ++kc) {
        if (kc < 7) {
#pragma unroll
          for (int t = 0; t < 4; ++t)
            bwn[t] = *(const bf16x8*)(w2e + (t*8 + kc + 1)*512);
        }
        bf16x8 a[4];
#pragma unroll
        for (int Mt = 0; Mt < 4; ++Mt)
          a[Mt] = *(const bf16x8*)(HsR + (Mt*16 + r)*XST + kc*32 + q*8);
#pragma unroll
        for (int Mt = 0; Mt < 4; ++Mt)
#pragma unroll
          for (int t = 0; t < 4; ++t)
            oacc[Mt][t] = __builtin_amdgcn_mfma_f32_16x16x32_bf16(a[Mt], bw[t], oacc[Mt][t], 0, 0, 0);
#pragma unroll
        for (int t = 0; t < 4; ++t) bw[t] = bwn[t];
      }
    }
    __syncthreads();   // Hs consumed; next expert may overwrite
  }

  // ---- epilogue: out = oacc + sum_e w[p,e]*b2[e,c] + x (fp32 residual) ----
  float b2v[4][4];   // [t][e] for c = wv*64 + t*16 + r
#pragma unroll
  for (int t = 0; t < 4; ++t) {
    const int c = wv*64 + t*16 + r;
#pragma unroll
    for (int e = 0; e < 4; ++e) b2v[t][e] = b2[e*256 + c];
  }

  float* ob = out + (size_t)b * C_DIM * S_DIM + s0;
#pragma unroll
  for (int Mt = 0; Mt < 4; ++Mt)
#pragma unroll
    for (int reg = 0; reg < 4; ++reg) {
      const int p = Mt*16 + q*4 + reg;
      const float w0 = Wgt[p*4+0], w1 = Wgt[p*4+1], w2 = Wgt[p*4+2], w3 = Wgt[p*4+3];
#pragma unroll
      for (int t = 0; t < 4; ++t) {
        const int c = wv*64 + t*16 + r;
        const float wsum = w0*b2v[t][0] + w1*b2v[t][1] + w2*b2v[t][2] + w3*b2v[t][3];
        ob[(size_t)c * S_DIM + p] = oacc[Mt][t][reg] + wsum + xb[(size_t)c * S_DIM + p];
      }
    }
}

extern "C" void kernel_launch(void* const* d_in, const int* in_sizes, int n_in,
                              void* d_out, int out_size, void* d_ws, size_t ws_size,
                              hipStream_t stream)
{
  (void)in_sizes; (void)n_in; (void)out_size; (void)ws_size;
  const float* x      = (const float*)d_in[0];
  const float* gate_w = (const float*)d_in[1];
  const float* gate_b = (const float*)d_in[2];
  const float* w1     = (const float*)d_in[3];
  const float* b1     = (const float*)d_in[4];
  const float* w2     = (const float*)d_in[5];
  const float* b2     = (const float*)d_in[6];
  float* out = (float*)d_out;
  __hip_bfloat16* wpack = (__hip_bfloat16*)d_ws;   // needs 1 MiB of scratch

  prepack_kernel<<<2048, 256, 0, stream>>>(w1, w2, wpack);
  moe_fused_kernel<<<512, 256, 0, stream>>>(x, gate_w, gate_b, b1, b2, wpack, out);
}

// Round 4
// 146.763 us; speedup vs baseline: 1.8930x; 1.0184x over previous
//
#include <hip/hip_runtime.h>
#include <hip/hip_bf16.h>

// MoE fused block, MI355X gfx950.
// Shapes: B=2, C=256, T*H*W=16384, E=4, K=2. All inputs fp32, output fp32.
//
// R3 -> R4 (VALU/latency diet; R3 was VALU-issue + scatter bound):
//  * SiLU: z * v_rcp(1+exp(-z)) instead of full-precision divide (~10 inst).
//  * Output epilogue: oacc(+b2 wsum) -> fp32 LDS O-tile (aliases dead Xs/Hs),
//    then coalesced float4 residual-add + store (was 16-line scatter insts).
//  * X staging: 4x4 register transpose -> ds_write_b64 (was 64 ds_write_b16).
//  * Global B-fragment prefetch depth 2 (ring of 3); GEMM2 kc0/kc1 loads
//    issued before the Hs barrier.

#define C_DIM 256
#define S_DIM 16384          // T*H*W
#define E_DIM 4
#define MT 64                // positions per workgroup
#define XST 264              // Xs/Hs row stride in shorts (16B-aligned rows)
#define OST 68               // O-tile row stride in floats (16B-aligned, conflict-free)
#define WFRAG_ELEMS 262144   // elements per prepacked weight tensor (4*16*8*64*8)

typedef __attribute__((ext_vector_type(8))) short bf16x8;
typedef __attribute__((ext_vector_type(4))) short short4v;
typedef __attribute__((ext_vector_type(4))) float f32x4;

__device__ __forceinline__ short bfq(float f) {
  __hip_bfloat16 h = __float2bfloat16(f);
  return *(short*)&h;
}

// Prepack: dst[(half,e,nt,kc,lane,j)] = src[(e*256 + nt*16 + (lane&15))*256
//                                           + kc*32 + (lane>>4)*8 + j]
// B-operand fragment layout for mfma_f32_16x16x32_bf16: n=lane&15, k=(lane>>4)*8+j.
__global__ __launch_bounds__(256) void prepack_kernel(
    const float* __restrict__ w1, const float* __restrict__ w2,
    __hip_bfloat16* __restrict__ dst)
{
  int o = blockIdx.x * 256 + threadIdx.x;   // 0 .. 524287
  int half = o >> 18;                       // 0: w1, 1: w2
  int idx = o & (WFRAG_ELEMS - 1);
  int j    = idx & 7;
  int lane = (idx >> 3) & 63;
  int kc   = (idx >> 9) & 7;
  int nt   = (idx >> 12) & 15;
  int e    = (idx >> 16) & 3;
  const float* src = half ? w2 : w1;
  int si = (e*256 + nt*16 + (lane & 15))*256 + kc*32 + (lane >> 4)*8 + j;
  dst[o] = __float2bfloat16(src[si]);
}

__global__ __launch_bounds__(256, 2) void moe_fused_kernel(
    const float* __restrict__ x,
    const float* __restrict__ gate_w,
    const float* __restrict__ gate_b,
    const float* __restrict__ b1,
    const float* __restrict__ b2,
    const __hip_bfloat16* __restrict__ wp,   // [W1P | W2P] prepacked bf16
    float* __restrict__ out)
{
  // pool: phase 1: Xs (33792 B) + Hs (33792 B). phase 2 (epilogue): O tile
  // 256 x OST fp32 = 69632 B. Total LDS = 69632 + 1024 -> 2 blocks/CU.
  __shared__ __align__(16) char pool[256 * OST * 4];
  __shared__ float Wgt[MT * 4];

  short* XsS = (short*)pool;
  short* HsS = (short*)(pool + MT * XST * 2);
  float* Os  = (float*)pool;

  const int tid  = threadIdx.x;
  const int lane = tid & 63;
  const int wv   = tid >> 6;     // wave 0..3: owns output n-slice [wv*64, wv*64+64)
  const int r    = lane & 15;
  const int q    = lane >> 4;

  const int g  = blockIdx.x;
  const int b  = g >> 8;                 // 256 workgroups per batch
  const int s0 = (g & 255) * MT;
  const float* xb = x + (size_t)b * C_DIM * S_DIM + s0;

  // ---- stage X tile: 4x4 register transpose, ds_write_b64 ----
  {
    const int p4 = (tid & 15) * 4;
    const int cg = tid >> 4;
#pragma unroll
    for (int cc = 0; cc < 4; ++cc) {
      const int c0 = (cc*16 + cg) * 4;
      const float4 v0 = *(const float4*)(xb + (size_t)(c0+0)*S_DIM + p4);
      const float4 v1 = *(const float4*)(xb + (size_t)(c0+1)*S_DIM + p4);
      const float4 v2 = *(const float4*)(xb + (size_t)(c0+2)*S_DIM + p4);
      const float4 v3 = *(const float4*)(xb + (size_t)(c0+3)*S_DIM + p4);
      *(short4v*)(XsS + (p4+0)*XST + c0) = (short4v){bfq(v0.x), bfq(v1.x), bfq(v2.x), bfq(v3.x)};
      *(short4v*)(XsS + (p4+1)*XST + c0) = (short4v){bfq(v0.y), bfq(v1.y), bfq(v2.y), bfq(v3.y)};
      *(short4v*)(XsS + (p4+2)*XST + c0) = (short4v){bfq(v0.z), bfq(v1.z), bfq(v2.z), bfq(v3.z)};
      *(short4v*)(XsS + (p4+3)*XST + c0) = (short4v){bfq(v0.w), bfq(v1.w), bfq(v2.w), bfq(v3.w)};
    }
  }

  // ---- gate logits in fp64 from ORIGINAL fp32 x (tie-flip-proof) ----
  {
    const int p = lane;
    const int e = wv;              // wave-uniform
    const float* gw = gate_w + e * C_DIM;
    const float* xr = xb + p;
    double a0 = 0.0, a1 = 0.0, a2 = 0.0, a3 = 0.0;
#pragma unroll 4
    for (int c = 0; c < C_DIM; c += 4) {
      a0 += (double)xr[(size_t)(c+0) * S_DIM] * (double)gw[c+0];
      a1 += (double)xr[(size_t)(c+1) * S_DIM] * (double)gw[c+1];
      a2 += (double)xr[(size_t)(c+2) * S_DIM] * (double)gw[c+2];
      a3 += (double)xr[(size_t)(c+3) * S_DIM] * (double)gw[c+3];
    }
    Wgt[p*4 + e] = (float)(((a0 + a1) + (a2 + a3)) + (double)gate_b[e]);
  }
  __syncthreads();   // Xs staged AND all logits written

  // ---- top-2 + softmax per position (first-index-wins, like top_k) ----
  if (tid < MT) {
    const int p = tid;
    const float l0 = Wgt[p*4+0], l1 = Wgt[p*4+1], l2 = Wgt[p*4+2], l3 = Wgt[p*4+3];
    int i1 = 0; float v1 = l0;
    if (l1 > v1) { v1 = l1; i1 = 1; }
    if (l2 > v1) { v1 = l2; i1 = 2; }
    if (l3 > v1) { v1 = l3; i1 = 3; }
    float v2 = -3.0e38f; int i2 = 0;
    if (i1 != 0 && l0 > v2) { v2 = l0; i2 = 0; }
    if (i1 != 1 && l1 > v2) { v2 = l1; i2 = 1; }
    if (i1 != 2 && l2 > v2) { v2 = l2; i2 = 2; }
    if (i1 != 3 && l3 > v2) { v2 = l3; i2 = 3; }
    const float wA = 1.0f / (1.0f + __expf(v2 - v1));
    const float wB = 1.0f - wA;
    Wgt[p*4+0] = (i1 == 0) ? wA : ((i2 == 0) ? wB : 0.0f);
    Wgt[p*4+1] = (i1 == 1) ? wA : ((i2 == 1) ? wB : 0.0f);
    Wgt[p*4+2] = (i1 == 2) ? wA : ((i2 == 2) ? wB : 0.0f);
    Wgt[p*4+3] = (i1 == 3) ? wA : ((i2 == 3) ? wB : 0.0f);
  }
  __syncthreads();   // Wgt final

  const short* W1P = (const short*)wp;
  const short* W2P = (const short*)wp + WFRAG_ELEMS;

  f32x4 oacc[4][4];   // [Mt][t]: persistent out accumulator, K=1024 concat
#pragma unroll
  for (int i = 0; i < 4; ++i)
#pragma unroll
    for (int j = 0; j < 4; ++j) oacc[i][j] = (f32x4){0.f, 0.f, 0.f, 0.f};

  for (int e = 0; e < E_DIM; ++e) {
    // ---- GEMM1: hacc[Mt][t] = X(64x256) @ W1_e^T slice, depth-2 prefetch ----
    f32x4 hacc[4][4];
#pragma unroll
    for (int i = 0; i < 4; ++i)
#pragma unroll
      for (int j = 0; j < 4; ++j) hacc[i][j] = (f32x4){0.f, 0.f, 0.f, 0.f};

    {
      const short* w1e = W1P + ((e*16 + wv*4)*8)*512 + lane*8;
      bf16x8 bw[3][4];
#pragma unroll
      for (int t = 0; t < 4; ++t) bw[0][t] = *(const bf16x8*)(w1e + (t*8 + 0)*512);
#pragma unroll
      for (int t = 0; t < 4; ++t) bw[1][t] = *(const bf16x8*)(w1e + (t*8 + 1)*512);
#pragma unroll
      for (int kc = 0; kc < 8; ++kc) {
        if (kc < 6) {
#pragma unroll
          for (int t = 0; t < 4; ++t)
            bw[(kc+2)%3][t] = *(const bf16x8*)(w1e + (t*8 + kc + 2)*512);
        }
        bf16x8 a[4];
#pragma unroll
        for (int Mt = 0; Mt < 4; ++Mt)
          a[Mt] = *(const bf16x8*)(XsS + (Mt*16 + r)*XST + kc*32 + q*8);
#pragma unroll
        for (int Mt = 0; Mt < 4; ++Mt)
#pragma unroll
          for (int t = 0; t < 4; ++t)
            hacc[Mt][t] = __builtin_amdgcn_mfma_f32_16x16x32_bf16(a[Mt], bw[kc%3][t], hacc[Mt][t], 0, 0, 0);
      }
    }

    // ---- prefetch GEMM2's first two kc B-fragments BEFORE the barrier ----
    const short* w2e = W2P + ((e*16 + wv*4)*8)*512 + lane*8;
    bf16x8 cw[3][4];
#pragma unroll
    for (int t = 0; t < 4; ++t) cw[0][t] = *(const bf16x8*)(w2e + (t*8 + 0)*512);
#pragma unroll
    for (int t = 0; t < 4; ++t) cw[1][t] = *(const bf16x8*)(w2e + (t*8 + 1)*512);

    // ---- H epilogue: +b1, fast SiLU, pre-scale by gate weight, write Hs ----
    {
      float wreg[4][4];
#pragma unroll
      for (int Mt = 0; Mt < 4; ++Mt)
#pragma unroll
        for (int reg = 0; reg < 4; ++reg)
          wreg[Mt][reg] = Wgt[(Mt*16 + q*4 + reg)*4 + e];
#pragma unroll
      for (int t = 0; t < 4; ++t) {
        const int n = wv*64 + t*16 + r;
        const float bias = b1[e*256 + n];
#pragma unroll
        for (int Mt = 0; Mt < 4; ++Mt)
#pragma unroll
          for (int reg = 0; reg < 4; ++reg) {
            const float z = hacc[Mt][t][reg] + bias;
            const float s = __builtin_amdgcn_rcpf(1.0f + __expf(-z));
            const float h = z * s * wreg[Mt][reg];
            HsS[(Mt*16 + q*4 + reg)*XST + n] = bfq(h);
          }
      }
    }
    __syncthreads();   // Hs complete

    // ---- GEMM2: oacc += H_e(64x256) @ W2_e^T slice, depth-2 prefetch ----
    {
#pragma unroll
      for (int kc = 0; kc < 8; ++kc) {
        if (kc < 6) {
#pragma unroll
          for (int t = 0; t < 4; ++t)
            cw[(kc+2)%3][t] = *(const bf16x8*)(w2e + (t*8 + kc + 2)*512);
        }
        bf16x8 a[4];
#pragma unroll
        for (int Mt = 0; Mt < 4; ++Mt)
          a[Mt] = *(const bf16x8*)(HsS + (Mt*16 + r)*XST + kc*32 + q*8);
#pragma unroll
        for (int Mt = 0; Mt < 4; ++Mt)
#pragma unroll
          for (int t = 0; t < 4; ++t)
            oacc[Mt][t] = __builtin_amdgcn_mfma_f32_16x16x32_bf16(a[Mt], cw[kc%3][t], oacc[Mt][t], 0, 0, 0);
      }
    }
    __syncthreads();   // Hs consumed; next expert may overwrite (also guards Os)
  }

  // ---- O epilogue part 1: oacc + b2-wsum -> fp32 LDS O tile (b128 writes) ----
  {
    float b2v[4][4];   // [t][e] for c = wv*64 + t*16 + r
#pragma unroll
    for (int t = 0; t < 4; ++t) {
      const int c = wv*64 + t*16 + r;
#pragma unroll
      for (int e = 0; e < 4; ++e) b2v[t][e] = b2[e*256 + c];
    }
#pragma unroll
    for (int Mt = 0; Mt < 4; ++Mt) {
      f32x4 wv4[4];
#pragma unroll
      for (int reg = 0; reg < 4; ++reg)
        wv4[reg] = *(const f32x4*)(&Wgt[(Mt*16 + q*4 + reg)*4]);
#pragma unroll
      for (int t = 0; t < 4; ++t) {
        f32x4 v = oacc[Mt][t];
#pragma unroll
        for (int reg = 0; reg < 4; ++reg)
          v[reg] += wv4[reg][0]*b2v[t][0] + wv4[reg][1]*b2v[t][1]
                  + wv4[reg][2]*b2v[t][2] + wv4[reg][3]*b2v[t][3];
        *(f32x4*)(Os + (size_t)(wv*64 + t*16 + r)*OST + Mt*16 + q*4) = v;
      }
    }
  }
  __syncthreads();

  // ---- O epilogue part 2: coalesced residual-add + float4 store ----
  {
    const int p4 = (tid & 15) * 4;
    const int cg = tid >> 4;
    float* ob = out + (size_t)b * C_DIM * S_DIM + s0;
#pragma unroll
    for (int cc = 0; cc < 16; ++cc) {
      const int c = cc*16 + cg;
      const f32x4  o  = *(const f32x4*)(Os + (size_t)c*OST + p4);
      const float4 xr = *(const float4*)(xb + (size_t)c*S_DIM + p4);
      float4 res;
      res.x = o[0] + xr.x; res.y = o[1] + xr.y;
      res.z = o[2] + xr.z; res.w = o[3] + xr.w;
      *(float4*)(ob + (size_t)c*S_DIM + p4) = res;
    }
  }
}

extern "C" void kernel_launch(void* const* d_in, const int* in_sizes, int n_in,
                              void* d_out, int out_size, void* d_ws, size_t ws_size,
                              hipStream_t stream)
{
  (void)in_sizes; (void)n_in; (void)out_size; (void)ws_size;
  const float* x      = (const float*)d_in[0];
  const float* gate_w = (const float*)d_in[1];
  const float* gate_b = (const float*)d_in[2];
  const float* w1     = (const float*)d_in[3];
  const float* b1     = (const float*)d_in[4];
  const float* w2     = (const float*)d_in[5];
  const float* b2     = (const float*)d_in[6];
  float* out = (float*)d_out;
  __hip_bfloat16* wpack = (__hip_bfloat16*)d_ws;   // needs 1 MiB of scratch

  prepack_kernel<<<2048, 256, 0, stream>>>(w1, w2, wpack);
  moe_fused_kernel<<<512, 256, 0, stream>>>(x, gate_w, gate_b, b1, b2, wpack, out);
}

// Round 5
// 136.941 us; speedup vs baseline: 2.0288x; 1.0717x over previous
//
#include <hip/hip_runtime.h>
#include <hip/hip_bf16.h>

// MoE fused block, MI355X gfx950.
// Shapes: B=2, C=256, T*H*W=16384, E=4, K=2. All inputs fp32, output fp32.
//
// R4 -> R5 (occupancy attack): R4 ran at 8 waves/CU (VGPR+AGPR ~256/wave, 2
// blocks/CU) -> latency-bound with nothing to hide it. Now 512-thread WGs:
// 8 waves each owning a 32-wide n-slice. Per-wave regs halve (hacc 32 +
// oacc 32 AGPR, ring-2 prefetch), __launch_bounds__(512,4) caps at 128 ->
// 4 waves/SIMD = 16 waves/CU. Weight reuse per load stays 1:4, device L2
// weight traffic stays 512 MB. Gate fp64 chain split in half across waves
// (fp64 partials in LDS, deterministic).

#define C_DIM 256
#define S_DIM 16384          // T*H*W
#define E_DIM 4
#define MT 64                // positions per workgroup
#define XST 264              // Xs/Hs row stride in shorts (16B-aligned rows)
#define OST 68               // O-tile row stride in floats (16B-aligned)
#define WFRAG_ELEMS 262144   // elements per prepacked weight tensor (4*16*8*64*8)

typedef __attribute__((ext_vector_type(8))) short bf16x8;
typedef __attribute__((ext_vector_type(4))) short short4v;
typedef __attribute__((ext_vector_type(4))) float f32x4;

__device__ __forceinline__ short bfq(float f) {
  __hip_bfloat16 h = __float2bfloat16(f);
  return *(short*)&h;
}

// Prepack: dst[(half,e,nt,kc,lane,j)] = src[(e*256 + nt*16 + (lane&15))*256
//                                           + kc*32 + (lane>>4)*8 + j]
// B-operand fragment layout for mfma_f32_16x16x32_bf16: n=lane&15, k=(lane>>4)*8+j.
__global__ __launch_bounds__(256) void prepack_kernel(
    const float* __restrict__ w1, const float* __restrict__ w2,
    __hip_bfloat16* __restrict__ dst)
{
  int o = blockIdx.x * 256 + threadIdx.x;   // 0 .. 524287
  int half = o >> 18;                       // 0: w1, 1: w2
  int idx = o & (WFRAG_ELEMS - 1);
  int j    = idx & 7;
  int lane = (idx >> 3) & 63;
  int kc   = (idx >> 9) & 7;
  int nt   = (idx >> 12) & 15;
  int e    = (idx >> 16) & 3;
  const float* src = half ? w2 : w1;
  int si = (e*256 + nt*16 + (lane & 15))*256 + kc*32 + (lane >> 4)*8 + j;
  dst[o] = __float2bfloat16(src[si]);
}

__global__ __launch_bounds__(512, 4) void moe_fused_kernel(
    const float* __restrict__ x,
    const float* __restrict__ gate_w,
    const float* __restrict__ gate_b,
    const float* __restrict__ b1,
    const float* __restrict__ b2,
    const __hip_bfloat16* __restrict__ wp,   // [W1P | W2P] prepacked bf16
    float* __restrict__ out)
{
  // pool (69632 B): phase 1 Xs (33792) + Hs (33792); epilogue O tile 256xOSTx4.
  // + Wgt 1024 + GateP 4096 = 74752 B -> 2 blocks/CU.
  __shared__ __align__(16) char pool[256 * OST * 4];
  __shared__ float Wgt[MT * 4];
  __shared__ double GateP[512];   // [half(2)][pos(64)][e(4)] fp64 partials

  short* XsS = (short*)pool;
  short* HsS = (short*)(pool + MT * XST * 2);
  float* Os  = (float*)pool;

  const int tid  = threadIdx.x;
  const int lane = tid & 63;
  const int wv   = tid >> 6;     // wave 0..7: owns n-slice [wv*32, wv*32+32)
  const int r    = lane & 15;
  const int q    = lane >> 4;

  const int g  = blockIdx.x;
  const int b  = g >> 8;                 // 256 workgroups per batch
  const int s0 = (g & 255) * MT;
  const float* xb = x + (size_t)b * C_DIM * S_DIM + s0;

  // ---- stage X tile: 4x4 register transpose, ds_write_b64 ----
  {
    const int p4 = (tid & 15) * 4;
    const int cg = tid >> 4;             // 0..31
#pragma unroll
    for (int cc = 0; cc < 2; ++cc) {
      const int c0 = (cc*32 + cg) * 4;
      const float4 v0 = *(const float4*)(xb + (size_t)(c0+0)*S_DIM + p4);
      const float4 v1 = *(const float4*)(xb + (size_t)(c0+1)*S_DIM + p4);
      const float4 v2 = *(const float4*)(xb + (size_t)(c0+2)*S_DIM + p4);
      const float4 v3 = *(const float4*)(xb + (size_t)(c0+3)*S_DIM + p4);
      *(short4v*)(XsS + (p4+0)*XST + c0) = (short4v){bfq(v0.x), bfq(v1.x), bfq(v2.x), bfq(v3.x)};
      *(short4v*)(XsS + (p4+1)*XST + c0) = (short4v){bfq(v0.y), bfq(v1.y), bfq(v2.y), bfq(v3.y)};
      *(short4v*)(XsS + (p4+2)*XST + c0) = (short4v){bfq(v0.z), bfq(v1.z), bfq(v2.z), bfq(v3.z)};
      *(short4v*)(XsS + (p4+3)*XST + c0) = (short4v){bfq(v0.w), bfq(v1.w), bfq(v2.w), bfq(v3.w)};
    }
  }

  // ---- gate logit fp64 partials from ORIGINAL fp32 x (tie-flip-proof) ----
  // wave wv: expert e = wv&3, c-half = wv>>2 (K=128 each -> half the chain).
  {
    const int p  = lane;
    const int e  = wv & 3;               // wave-uniform
    const int ch = wv >> 2;              // wave-uniform
    const float* gw = gate_w + e * C_DIM + ch * 128;
    const float* xr = xb + p + (size_t)(ch * 128) * S_DIM;
    double a0 = 0.0, a1 = 0.0, a2 = 0.0, a3 = 0.0;
#pragma unroll 4
    for (int c = 0; c < 128; c += 4) {
      a0 += (double)xr[(size_t)(c+0) * S_DIM] * (double)gw[c+0];
      a1 += (double)xr[(size_t)(c+1) * S_DIM] * (double)gw[c+1];
      a2 += (double)xr[(size_t)(c+2) * S_DIM] * (double)gw[c+2];
      a3 += (double)xr[(size_t)(c+3) * S_DIM] * (double)gw[c+3];
    }
    GateP[(ch*64 + p)*4 + e] = (a0 + a1) + (a2 + a3);
  }
  __syncthreads();   // Xs staged AND all gate partials written

  // ---- combine halves + top-2 + softmax (thread p < 64) ----
  if (tid < MT) {
    const int p = tid;
    float l[4];
#pragma unroll
    for (int e = 0; e < 4; ++e)
      l[e] = (float)(GateP[p*4 + e] + GateP[(64 + p)*4 + e] + (double)gate_b[e]);
    int i1 = 0; float v1 = l[0];
    if (l[1] > v1) { v1 = l[1]; i1 = 1; }
    if (l[2] > v1) { v1 = l[2]; i1 = 2; }
    if (l[3] > v1) { v1 = l[3]; i1 = 3; }
    float v2 = -3.0e38f; int i2 = 0;
    if (i1 != 0 && l[0] > v2) { v2 = l[0]; i2 = 0; }
    if (i1 != 1 && l[1] > v2) { v2 = l[1]; i2 = 1; }
    if (i1 != 2 && l[2] > v2) { v2 = l[2]; i2 = 2; }
    if (i1 != 3 && l[3] > v2) { v2 = l[3]; i2 = 3; }
    const float wA = 1.0f / (1.0f + __expf(v2 - v1));
    const float wB = 1.0f - wA;
    Wgt[p*4+0] = (i1 == 0) ? wA : ((i2 == 0) ? wB : 0.0f);
    Wgt[p*4+1] = (i1 == 1) ? wA : ((i2 == 1) ? wB : 0.0f);
    Wgt[p*4+2] = (i1 == 2) ? wA : ((i2 == 2) ? wB : 0.0f);
    Wgt[p*4+3] = (i1 == 3) ? wA : ((i2 == 3) ? wB : 0.0f);
  }
  __syncthreads();   // Wgt final

  const short* W1P = (const short*)wp;
  const short* W2P = (const short*)wp + WFRAG_ELEMS;

  f32x4 oacc[4][2];   // [Mt][t]: persistent out accumulator, K=1024 concat
#pragma unroll
  for (int i = 0; i < 4; ++i)
#pragma unroll
    for (int j = 0; j < 2; ++j) oacc[i][j] = (f32x4){0.f, 0.f, 0.f, 0.f};

  for (int e = 0; e < E_DIM; ++e) {
    // ---- GEMM1: hacc[Mt][t] = X(64x256) @ W1_e^T slice, ring-2 prefetch ----
    f32x4 hacc[4][2];
#pragma unroll
    for (int i = 0; i < 4; ++i)
#pragma unroll
      for (int j = 0; j < 2; ++j) hacc[i][j] = (f32x4){0.f, 0.f, 0.f, 0.f};

    {
      const short* w1e = W1P + ((e*16 + wv*2)*8)*512 + lane*8;
      bf16x8 bw[2][2];
#pragma unroll
      for (int t = 0; t < 2; ++t) bw[0][t] = *(const bf16x8*)(w1e + (t*8 + 0)*512);
#pragma unroll
      for (int kc = 0; kc < 8; ++kc) {
        if (kc < 7) {
#pragma unroll
          for (int t = 0; t < 2; ++t)
            bw[(kc+1)&1][t] = *(const bf16x8*)(w1e + (t*8 + kc + 1)*512);
        }
        bf16x8 a[4];
#pragma unroll
        for (int Mt = 0; Mt < 4; ++Mt)
          a[Mt] = *(const bf16x8*)(XsS + (Mt*16 + r)*XST + kc*32 + q*8);
#pragma unroll
        for (int Mt = 0; Mt < 4; ++Mt)
#pragma unroll
          for (int t = 0; t < 2; ++t)
            hacc[Mt][t] = __builtin_amdgcn_mfma_f32_16x16x32_bf16(a[Mt], bw[kc&1][t], hacc[Mt][t], 0, 0, 0);
      }
    }

    // ---- prefetch GEMM2's first kc B-fragments BEFORE the barrier ----
    const short* w2e = W2P + ((e*16 + wv*2)*8)*512 + lane*8;
    bf16x8 cw[2][2];
#pragma unroll
    for (int t = 0; t < 2; ++t) cw[0][t] = *(const bf16x8*)(w2e + (t*8 + 0)*512);

    // ---- H epilogue: +b1, fast SiLU, pre-scale by gate weight, write Hs ----
    {
      float wreg[4][4];
#pragma unroll
      for (int Mt = 0; Mt < 4; ++Mt)
#pragma unroll
        for (int reg = 0; reg < 4; ++reg)
          wreg[Mt][reg] = Wgt[(Mt*16 + q*4 + reg)*4 + e];
#pragma unroll
      for (int t = 0; t < 2; ++t) {
        const int n = wv*32 + t*16 + r;
        const float bias = b1[e*256 + n];
#pragma unroll
        for (int Mt = 0; Mt < 4; ++Mt)
#pragma unroll
          for (int reg = 0; reg < 4; ++reg) {
            const float z = hacc[Mt][t][reg] + bias;
            const float s = __builtin_amdgcn_rcpf(1.0f + __expf(-z));
            const float h = z * s * wreg[Mt][reg];
            HsS[(Mt*16 + q*4 + reg)*XST + n] = bfq(h);
          }
      }
    }
    __syncthreads();   // Hs complete

    // ---- GEMM2: oacc += H_e(64x256) @ W2_e^T slice, ring-2 prefetch ----
    {
#pragma unroll
      for (int kc = 0; kc < 8; ++kc) {
        if (kc < 7) {
#pragma unroll
          for (int t = 0; t < 2; ++t)
            cw[(kc+1)&1][t] = *(const bf16x8*)(w2e + (t*8 + kc + 1)*512);
        }
        bf16x8 a[4];
#pragma unroll
        for (int Mt = 0; Mt < 4; ++Mt)
          a[Mt] = *(const bf16x8*)(HsS + (Mt*16 + r)*XST + kc*32 + q*8);
#pragma unroll
        for (int Mt = 0; Mt < 4; ++Mt)
#pragma unroll
          for (int t = 0; t < 2; ++t)
            oacc[Mt][t] = __builtin_amdgcn_mfma_f32_16x16x32_bf16(a[Mt], cw[kc&1][t], oacc[Mt][t], 0, 0, 0);
      }
    }
    __syncthreads();   // Hs consumed; next expert may overwrite (guards Os too)
  }

  // ---- O epilogue part 1: oacc + b2-wsum -> fp32 LDS O tile (b128 writes) ----
  {
    float b2v[2][4];   // [t][e] for c = wv*32 + t*16 + r
#pragma unroll
    for (int t = 0; t < 2; ++t) {
      const int c = wv*32 + t*16 + r;
#pragma unroll
      for (int e = 0; e < 4; ++e) b2v[t][e] = b2[e*256 + c];
    }
#pragma unroll
    for (int Mt = 0; Mt < 4; ++Mt) {
      f32x4 wv4[4];
#pragma unroll
      for (int reg = 0; reg < 4; ++reg)
        wv4[reg] = *(const f32x4*)(&Wgt[(Mt*16 + q*4 + reg)*4]);
#pragma unroll
      for (int t = 0; t < 2; ++t) {
        f32x4 v = oacc[Mt][t];
#pragma unroll
        for (int reg = 0; reg < 4; ++reg)
          v[reg] += wv4[reg][0]*b2v[t][0] + wv4[reg][1]*b2v[t][1]
                  + wv4[reg][2]*b2v[t][2] + wv4[reg][3]*b2v[t][3];
        *(f32x4*)(Os + (size_t)(wv*32 + t*16 + r)*OST + Mt*16 + q*4) = v;
      }
    }
  }
  __syncthreads();

  // ---- O epilogue part 2: coalesced residual-add + float4 store ----
  {
    const int p4 = (tid & 15) * 4;
    const int cg = tid >> 4;             // 0..31
    float* ob = out + (size_t)b * C_DIM * S_DIM + s0;
#pragma unroll
    for (int cc = 0; cc < 8; ++cc) {
      const int c = cc*32 + cg;
      const f32x4  o  = *(const f32x4*)(Os + (size_t)c*OST + p4);
      const float4 xr = *(const float4*)(xb + (size_t)c*S_DIM + p4);
      float4 res;
      res.x = o[0] + xr.x; res.y = o[1] + xr.y;
      res.z = o[2] + xr.z; res.w = o[3] + xr.w;
      *(float4*)(ob + (size_t)c*S_DIM + p4) = res;
    }
  }
}

extern "C" void kernel_launch(void* const* d_in, const int* in_sizes, int n_in,
                              void* d_out, int out_size, void* d_ws, size_t ws_size,
                              hipStream_t stream)
{
  (void)in_sizes; (void)n_in; (void)out_size; (void)ws_size;
  const float* x      = (const float*)d_in[0];
  const float* gate_w = (const float*)d_in[1];
  const float* gate_b = (const float*)d_in[2];
  const float* w1     = (const float*)d_in[3];
  const float* b1     = (const float*)d_in[4];
  const float* w2     = (const float*)d_in[5];
  const float* b2     = (const float*)d_in[6];
  float* out = (float*)d_out;
  __hip_bfloat16* wpack = (__hip_bfloat16*)d_ws;   // needs 1 MiB of scratch

  prepack_kernel<<<2048, 256, 0, stream>>>(w1, w2, wpack);
  moe_fused_kernel<<<512, 512, 0, stream>>>(x, gate_w, gate_b, b1, b2, wpack, out);
}

// Round 6
// 136.627 us; speedup vs baseline: 2.0335x; 1.0023x over previous
//
#include <hip/hip_runtime.h>
#include <hip/hip_bf16.h>

// MoE fused block, MI355X gfx950.
// Shapes: B=2, C=256, T*H*W=16384, E=4, K=2. All inputs fp32, output fp32.
//
// R5 -> R6 (top-2 sparsity on GEMM1): per expert, ballot-gather the positions
// with nonzero gate weight into plist[e] (LDS), run GEMM1 only on
// ceil(m_e/16) M-tiles (E ~ 2.5 vs 4 dense), scatter SiLU'd+scaled H rows to
// dense Hs, zero-fill complement rows. GEMM2 stays dense (zero rows give 0),
// so oacc/barriers/epilogue are unchanged. Tail-tile pad entries point at
// complement rows with gate weight 0 (write exact 0; benign vs zero-fill).
// Register budget guarded: unified regs must stay <=128 (4 waves/SIMD).

#define C_DIM 256
#define S_DIM 16384          // T*H*W
#define E_DIM 4
#define MT 64                // positions per workgroup
#define XST 264              // Xs/Hs row stride in shorts (16B-aligned rows)
#define OST 68               // O-tile row stride in floats (16B-aligned)
#define WFRAG_ELEMS 262144   // elements per prepacked weight tensor (4*16*8*64*8)

typedef __attribute__((ext_vector_type(8))) short bf16x8;
typedef __attribute__((ext_vector_type(4))) short short4v;
typedef __attribute__((ext_vector_type(4))) float f32x4;

__device__ __forceinline__ short bfq(float f) {
  __hip_bfloat16 h = __float2bfloat16(f);
  return *(short*)&h;
}

// Prepack: dst[(half,e,nt,kc,lane,j)] = src[(e*256 + nt*16 + (lane&15))*256
//                                           + kc*32 + (lane>>4)*8 + j]
// B-operand fragment layout for mfma_f32_16x16x32_bf16: n=lane&15, k=(lane>>4)*8+j.
__global__ __launch_bounds__(256) void prepack_kernel(
    const float* __restrict__ w1, const float* __restrict__ w2,
    __hip_bfloat16* __restrict__ dst)
{
  int o = blockIdx.x * 256 + threadIdx.x;   // 0 .. 524287
  int half = o >> 18;                       // 0: w1, 1: w2
  int idx = o & (WFRAG_ELEMS - 1);
  int j    = idx & 7;
  int lane = (idx >> 3) & 63;
  int kc   = (idx >> 9) & 7;
  int nt   = (idx >> 12) & 15;
  int e    = (idx >> 16) & 3;
  const float* src = half ? w2 : w1;
  int si = (e*256 + nt*16 + (lane & 15))*256 + kc*32 + (lane >> 4)*8 + j;
  dst[o] = __float2bfloat16(src[si]);
}

// GEMM1 over MTC gathered M-tiles + SiLU/scale epilogue scattering into Hs.
template<int MTC>
__device__ __forceinline__ void gemm1_sparse(
    const short* XsS, short* HsS, const short* w1e, const float* b1e,
    const unsigned char* plist_e, const float* wgtg_e,
    int wv, int r, int q)
{
  f32x4 hacc[MTC][2];
#pragma unroll
  for (int i = 0; i < MTC; ++i)
#pragma unroll
    for (int j = 0; j < 2; ++j) hacc[i][j] = (f32x4){0.f, 0.f, 0.f, 0.f};

  int aoff[MTC];
#pragma unroll
  for (int Mt = 0; Mt < MTC; ++Mt)
    aoff[Mt] = (int)plist_e[Mt*16 + r] * XST;

  bf16x8 bw[2][2];
#pragma unroll
  for (int t = 0; t < 2; ++t) bw[0][t] = *(const bf16x8*)(w1e + (t*8 + 0)*512);
#pragma unroll
  for (int kc = 0; kc < 8; ++kc) {
    if (kc < 7) {
#pragma unroll
      for (int t = 0; t < 2; ++t)
        bw[(kc+1)&1][t] = *(const bf16x8*)(w1e + (t*8 + kc + 1)*512);
    }
    bf16x8 a[MTC];
#pragma unroll
    for (int Mt = 0; Mt < MTC; ++Mt)
      a[Mt] = *(const bf16x8*)(XsS + aoff[Mt] + kc*32 + q*8);
#pragma unroll
    for (int Mt = 0; Mt < MTC; ++Mt)
#pragma unroll
      for (int t = 0; t < 2; ++t)
        hacc[Mt][t] = __builtin_amdgcn_mfma_f32_16x16x32_bf16(a[Mt], bw[kc&1][t], hacc[Mt][t], 0, 0, 0);
  }

  // epilogue: +b1, fast SiLU, scale by gathered gate weight, scatter to Hs
#pragma unroll
  for (int Mt = 0; Mt < MTC; ++Mt) {
    const int g0 = Mt*16 + q*4;
    const unsigned pw = *(const unsigned*)(plist_e + g0);   // 4 packed positions
    const f32x4 wg = *(const f32x4*)(wgtg_e + g0);
#pragma unroll
    for (int t = 0; t < 2; ++t) {
      const int n = wv*32 + t*16 + r;
      const float bias = b1e[n];
#pragma unroll
      for (int reg = 0; reg < 4; ++reg) {
        const int p = (pw >> (8*reg)) & 255;
        const float z = hacc[Mt][t][reg] + bias;
        const float s = __builtin_amdgcn_rcpf(1.0f + __expf(-z));
        HsS[p*XST + n] = bfq(z * s * wg[reg]);
      }
    }
  }
}

__global__ __launch_bounds__(512, 4) void moe_fused_kernel(
    const float* __restrict__ x,
    const float* __restrict__ gate_w,
    const float* __restrict__ gate_b,
    const float* __restrict__ b1,
    const float* __restrict__ b2,
    const __hip_bfloat16* __restrict__ wp,   // [W1P | W2P] prepacked bf16
    float* __restrict__ out)
{
  // pool (69632 B): phase 1 Xs (33792) + Hs (33792); epilogue O tile 256xOSTx4.
  // + Wgt 1KB + GateP 4KB + lists ~1.5KB ~= 76.3 KB -> 2 blocks/CU.
  __shared__ __align__(16) char pool[256 * OST * 4];
  __shared__ float Wgt[MT * 4];
  __shared__ double GateP[512];                         // [half][pos][e] fp64 partials
  __shared__ __align__(16) unsigned char plist[4][64];  // gathered positions
  __shared__ __align__(16) float WgtG[4][64];           // gathered gate weights
  __shared__ __align__(4)  unsigned char zlist[4][64];  // complement positions
  __shared__ int mcnt[4];

  short* XsS = (short*)pool;
  short* HsS = (short*)(pool + MT * XST * 2);
  float* Os  = (float*)pool;

  const int tid  = threadIdx.x;
  const int lane = tid & 63;
  const int wv   = tid >> 6;     // wave 0..7: owns n-slice [wv*32, wv*32+32)
  const int r    = lane & 15;
  const int q    = lane >> 4;

  const int g  = blockIdx.x;
  const int b  = g >> 8;                 // 256 workgroups per batch
  const int s0 = (g & 255) * MT;
  const float* xb = x + (size_t)b * C_DIM * S_DIM + s0;

  // ---- stage X tile: 4x4 register transpose, ds_write_b64 ----
  {
    const int p4 = (tid & 15) * 4;
    const int cg = tid >> 4;             // 0..31
#pragma unroll
    for (int cc = 0; cc < 2; ++cc) {
      const int c0 = (cc*32 + cg) * 4;
      const float4 v0 = *(const float4*)(xb + (size_t)(c0+0)*S_DIM + p4);
      const float4 v1 = *(const float4*)(xb + (size_t)(c0+1)*S_DIM + p4);
      const float4 v2 = *(const float4*)(xb + (size_t)(c0+2)*S_DIM + p4);
      const float4 v3 = *(const float4*)(xb + (size_t)(c0+3)*S_DIM + p4);
      *(short4v*)(XsS + (p4+0)*XST + c0) = (short4v){bfq(v0.x), bfq(v1.x), bfq(v2.x), bfq(v3.x)};
      *(short4v*)(XsS + (p4+1)*XST + c0) = (short4v){bfq(v0.y), bfq(v1.y), bfq(v2.y), bfq(v3.y)};
      *(short4v*)(XsS + (p4+2)*XST + c0) = (short4v){bfq(v0.z), bfq(v1.z), bfq(v2.z), bfq(v3.z)};
      *(short4v*)(XsS + (p4+3)*XST + c0) = (short4v){bfq(v0.w), bfq(v1.w), bfq(v2.w), bfq(v3.w)};
    }
  }

  // ---- gate logit fp64 partials from ORIGINAL fp32 x (tie-flip-proof) ----
  {
    const int p  = lane;
    const int e  = wv & 3;               // wave-uniform
    const int ch = wv >> 2;              // wave-uniform
    const float* gw = gate_w + e * C_DIM + ch * 128;
    const float* xr = xb + p + (size_t)(ch * 128) * S_DIM;
    double a0 = 0.0, a1 = 0.0, a2 = 0.0, a3 = 0.0;
#pragma unroll 4
    for (int c = 0; c < 128; c += 4) {
      a0 += (double)xr[(size_t)(c+0) * S_DIM] * (double)gw[c+0];
      a1 += (double)xr[(size_t)(c+1) * S_DIM] * (double)gw[c+1];
      a2 += (double)xr[(size_t)(c+2) * S_DIM] * (double)gw[c+2];
      a3 += (double)xr[(size_t)(c+3) * S_DIM] * (double)gw[c+3];
    }
    GateP[(ch*64 + p)*4 + e] = (a0 + a1) + (a2 + a3);
  }
  __syncthreads();   // Xs staged AND all gate partials written

  // ---- combine halves + top-2 + softmax (thread p < 64) ----
  if (tid < MT) {
    const int p = tid;
    float l[4];
#pragma unroll
    for (int e = 0; e < 4; ++e)
      l[e] = (float)(GateP[p*4 + e] + GateP[(64 + p)*4 + e] + (double)gate_b[e]);
    int i1 = 0; float v1 = l[0];
    if (l[1] > v1) { v1 = l[1]; i1 = 1; }
    if (l[2] > v1) { v1 = l[2]; i1 = 2; }
    if (l[3] > v1) { v1 = l[3]; i1 = 3; }
    float v2 = -3.0e38f; int i2 = 0;
    if (i1 != 0 && l[0] > v2) { v2 = l[0]; i2 = 0; }
    if (i1 != 1 && l[1] > v2) { v2 = l[1]; i2 = 1; }
    if (i1 != 2 && l[2] > v2) { v2 = l[2]; i2 = 2; }
    if (i1 != 3 && l[3] > v2) { v2 = l[3]; i2 = 3; }
    const float wA = 1.0f / (1.0f + __expf(v2 - v1));
    const float wB = 1.0f - wA;
    Wgt[p*4+0] = (i1 == 0) ? wA : ((i2 == 0) ? wB : 0.0f);
    Wgt[p*4+1] = (i1 == 1) ? wA : ((i2 == 1) ? wB : 0.0f);
    Wgt[p*4+2] = (i1 == 2) ? wA : ((i2 == 2) ? wB : 0.0f);
    Wgt[p*4+3] = (i1 == 3) ? wA : ((i2 == 3) ? wB : 0.0f);
  }
  __syncthreads();   // Wgt final

  // ---- per-expert gather lists via ballot (waves 0..3) ----
  if (wv < 4) {
    const int e = wv;
    const int p = lane;
    const float w = Wgt[p*4 + e];
    const bool sel = (w != 0.0f);
    const unsigned long long mask = __ballot(sel);
    const int below = __popcll(mask & ((1ull << p) - 1ull));
    const int m = __popcll(mask);
    const int pad = (((m + 15) >> 4) << 4) - m;
    if (sel) {
      plist[e][below] = (unsigned char)p;
      WgtG[e][below]  = w;
    } else {
      const int zidx = p - below;
      zlist[e][zidx] = (unsigned char)p;
      if (zidx < pad) {   // tail-tile padding: weight-0 complement rows
        plist[e][m + zidx] = (unsigned char)p;
        WgtG[e][m + zidx]  = 0.0f;
      }
    }
    if (p == 0) mcnt[e] = m;
  }
  __syncthreads();   // lists final

  const short* W1P = (const short*)wp;
  const short* W2P = (const short*)wp + WFRAG_ELEMS;

  f32x4 oacc[4][2];   // [Mt][t]: persistent out accumulator, K=1024 concat
#pragma unroll
  for (int i = 0; i < 4; ++i)
#pragma unroll
    for (int j = 0; j < 2; ++j) oacc[i][j] = (f32x4){0.f, 0.f, 0.f, 0.f};

  for (int e = 0; e < E_DIM; ++e) {
    const int me = mcnt[e];   // WG-uniform
    const int mt = __builtin_amdgcn_readfirstlane((me + 15) >> 4);
    const short* w1e = W1P + ((e*16 + wv*2)*8)*512 + lane*8;
    const float* b1e = b1 + e*256;

    if      (mt == 2) gemm1_sparse<2>(XsS, HsS, w1e, b1e, plist[e], WgtG[e], wv, r, q);
    else if (mt == 3) gemm1_sparse<3>(XsS, HsS, w1e, b1e, plist[e], WgtG[e], wv, r, q);
    else if (mt == 4) gemm1_sparse<4>(XsS, HsS, w1e, b1e, plist[e], WgtG[e], wv, r, q);
    else if (mt == 1) gemm1_sparse<1>(XsS, HsS, w1e, b1e, plist[e], WgtG[e], wv, r, q);
    // mt == 0: no positions use expert e; Hs fully zero-filled below.

    // prefetch GEMM2's first kc B-fragments before the barrier
    const short* w2e = W2P + ((e*16 + wv*2)*8)*512 + lane*8;
    bf16x8 cw[2][2];
#pragma unroll
    for (int t = 0; t < 2; ++t) cw[0][t] = *(const bf16x8*)(w2e + (t*8 + 0)*512);

    // zero-fill complement rows of Hs (positions not using expert e)
    {
      const int zm = 64 - me;
      const bf16x8 zz = {0,0,0,0,0,0,0,0};
      for (int i = tid; i < zm*32; i += 512) {
        const int row = zlist[e][i >> 5];
        *(bf16x8*)(HsS + row*XST + (i & 31)*8) = zz;
      }
    }
    __syncthreads();   // Hs complete (gathered writes + zero fill)

    // ---- GEMM2: oacc += H_e(64x256) @ W2_e^T slice, ring-2 prefetch ----
    {
#pragma unroll
      for (int kc = 0; kc < 8; ++kc) {
        if (kc < 7) {
#pragma unroll
          for (int t = 0; t < 2; ++t)
            cw[(kc+1)&1][t] = *(const bf16x8*)(w2e + (t*8 + kc + 1)*512);
        }
        bf16x8 a[4];
#pragma unroll
        for (int Mt = 0; Mt < 4; ++Mt)
          a[Mt] = *(const bf16x8*)(HsS + (Mt*16 + r)*XST + kc*32 + q*8);
#pragma unroll
        for (int Mt = 0; Mt < 4; ++Mt)
#pragma unroll
          for (int t = 0; t < 2; ++t)
            oacc[Mt][t] = __builtin_amdgcn_mfma_f32_16x16x32_bf16(a[Mt], cw[kc&1][t], oacc[Mt][t], 0, 0, 0);
      }
    }
    __syncthreads();   // Hs consumed; next expert may overwrite (guards Os too)
  }

  // ---- O epilogue part 1: oacc + b2-wsum -> fp32 LDS O tile (b128 writes) ----
  {
    float b2v[2][4];   // [t][e] for c = wv*32 + t*16 + r
#pragma unroll
    for (int t = 0; t < 2; ++t) {
      const int c = wv*32 + t*16 + r;
#pragma unroll
      for (int e = 0; e < 4; ++e) b2v[t][e] = b2[e*256 + c];
    }
#pragma unroll
    for (int Mt = 0; Mt < 4; ++Mt) {
      f32x4 wv4[4];
#pragma unroll
      for (int reg = 0; reg < 4; ++reg)
        wv4[reg] = *(const f32x4*)(&Wgt[(Mt*16 + q*4 + reg)*4]);
#pragma unroll
      for (int t = 0; t < 2; ++t) {
        f32x4 v = oacc[Mt][t];
#pragma unroll
        for (int reg = 0; reg < 4; ++reg)
          v[reg] += wv4[reg][0]*b2v[t][0] + wv4[reg][1]*b2v[t][1]
                  + wv4[reg][2]*b2v[t][2] + wv4[reg][3]*b2v[t][3];
        *(f32x4*)(Os + (size_t)(wv*32 + t*16 + r)*OST + Mt*16 + q*4) = v;
      }
    }
  }
  __syncthreads();

  // ---- O epilogue part 2: coalesced residual-add + float4 store ----
  {
    const int p4 = (tid & 15) * 4;
    const int cg = tid >> 4;             // 0..31
    float* ob = out + (size_t)b * C_DIM * S_DIM + s0;
#pragma unroll
    for (int cc = 0; cc < 8; ++cc) {
      const int c = cc*32 + cg;
      const f32x4  o  = *(const f32x4*)(Os + (size_t)c*OST + p4);
      const float4 xr = *(const float4*)(xb + (size_t)c*S_DIM + p4);
      float4 res;
      res.x = o[0] + xr.x; res.y = o[1] + xr.y;
      res.z = o[2] + xr.z; res.w = o[3] + xr.w;
      *(float4*)(ob + (size_t)c*S_DIM + p4) = res;
    }
  }
}

extern "C" void kernel_launch(void* const* d_in, const int* in_sizes, int n_in,
                              void* d_out, int out_size, void* d_ws, size_t ws_size,
                              hipStream_t stream)
{
  (void)in_sizes; (void)n_in; (void)out_size; (void)ws_size;
  const float* x      = (const float*)d_in[0];
  const float* gate_w = (const float*)d_in[1];
  const float* gate_b = (const float*)d_in[2];
  const float* w1     = (const float*)d_in[3];
  const float* b1     = (const float*)d_in[4];
  const float* w2     = (const float*)d_in[5];
  const float* b2     = (const float*)d_in[6];
  float* out = (float*)d_out;
  __hip_bfloat16* wpack = (__hip_bfloat16*)d_ws;   // needs 1 MiB of scratch

  prepack_kernel<<<2048, 256, 0, stream>>>(w1, w2, wpack);
  moe_fused_kernel<<<512, 512, 0, stream>>>(x, gate_w, gate_b, b1, b2, wpack, out);
}

// Round 7
// 128.241 us; speedup vs baseline: 2.1665x; 1.0654x over previous
//
#include <hip/hip_runtime.h>
#include <hip/hip_bf16.h>

// MoE fused block, MI355X gfx950.
// Shapes: B=2, C=256, T*H*W=16384, E=4, K=2. All inputs fp32, output fp32.
//
// R6 -> R7:
//  * Fused staging+gate: one pass over x (wave = 32-ch group, lane = position;
//    32 coalesced scalar loads), fp64 gate partials computed from the regs
//    already holding x, Xs written as b128, partials reduced via LDS (aliased
//    over Hs) + in-wave shuffles. Kills the gate's separate 64MB x re-read
//    and its serial load+fp64 prologue chain.
//  * Post-GEMM2 barrier moved inside GEMM1(e+1), just before the H-scatter:
//    GEMM2 stragglers are absorbed by independent GEMM1 compute.
//  * Prepack vectorized: 8 elems/thread (float4 x2 -> b128), 256 blocks.

#define C_DIM 256
#define S_DIM 16384          // T*H*W
#define E_DIM 4
#define MT 64                // positions per workgroup
#define XST 264              // Xs/Hs row stride in shorts (16B-aligned rows)
#define OST 68               // O-tile row stride in floats (16B-aligned)
#define WFRAG_ELEMS 262144   // elements per prepacked weight tensor (4*16*8*64*8)

typedef __attribute__((ext_vector_type(8))) short bf16x8;
typedef __attribute__((ext_vector_type(4))) float f32x4;

__device__ __forceinline__ short bfq(float f) {
  __hip_bfloat16 h = __float2bfloat16(f);
  return *(short*)&h;
}

// Prepack: dst[(half,e,nt,kc,lane,j)] = src[(e*256 + nt*16 + (lane&15))*256
//                                           + kc*32 + (lane>>4)*8 + j]
// B-operand fragment layout for mfma_f32_16x16x32_bf16: n=lane&15, k=(lane>>4)*8+j.
// 8 elements per thread: contiguous 32B read, 16B write.
__global__ __launch_bounds__(256) void prepack_kernel(
    const float* __restrict__ w1, const float* __restrict__ w2,
    __hip_bfloat16* __restrict__ dst)
{
  int o8 = blockIdx.x * 256 + threadIdx.x;   // 0 .. 65535
  int o  = o8 << 3;
  int half = o >> 18;                        // 0: w1, 1: w2
  int idx  = o & (WFRAG_ELEMS - 1);
  int lane = (idx >> 3) & 63;
  int kc   = (idx >> 9) & 7;
  int nt   = (idx >> 12) & 15;
  int e    = (idx >> 16) & 3;
  const float* src = half ? w2 : w1;
  const float* s = src + (e*256 + nt*16 + (lane & 15))*256 + kc*32 + (lane >> 4)*8;
  const float4 v0 = *(const float4*)s;
  const float4 v1 = *(const float4*)(s + 4);
  bf16x8 outv = {bfq(v0.x), bfq(v0.y), bfq(v0.z), bfq(v0.w),
                 bfq(v1.x), bfq(v1.y), bfq(v1.z), bfq(v1.w)};
  *(bf16x8*)((short*)dst + o) = outv;
}

// GEMM1 over MTC gathered M-tiles; barrier (protecting Hs readers of the
// previous expert's GEMM2) sits BETWEEN the MFMA loop and the H-scatter.
template<int MTC>
__device__ __forceinline__ void gemm1_sparse(
    const short* XsS, short* HsS, const short* w1e, const float* b1e,
    const unsigned char* plist_e, const float* wgtg_e,
    int wv, int r, int q, bool dosync)
{
  f32x4 hacc[MTC][2];
#pragma unroll
  for (int i = 0; i < MTC; ++i)
#pragma unroll
    for (int j = 0; j < 2; ++j) hacc[i][j] = (f32x4){0.f, 0.f, 0.f, 0.f};

  int aoff[MTC];
#pragma unroll
  for (int Mt = 0; Mt < MTC; ++Mt)
    aoff[Mt] = (int)plist_e[Mt*16 + r] * XST;

  bf16x8 bw[2][2];
#pragma unroll
  for (int t = 0; t < 2; ++t) bw[0][t] = *(const bf16x8*)(w1e + (t*8 + 0)*512);
#pragma unroll
  for (int kc = 0; kc < 8; ++kc) {
    if (kc < 7) {
#pragma unroll
      for (int t = 0; t < 2; ++t)
        bw[(kc+1)&1][t] = *(const bf16x8*)(w1e + (t*8 + kc + 1)*512);
    }
    bf16x8 a[MTC];
#pragma unroll
    for (int Mt = 0; Mt < MTC; ++Mt)
      a[Mt] = *(const bf16x8*)(XsS + aoff[Mt] + kc*32 + q*8);
#pragma unroll
    for (int Mt = 0; Mt < MTC; ++Mt)
#pragma unroll
      for (int t = 0; t < 2; ++t)
        hacc[Mt][t] = __builtin_amdgcn_mfma_f32_16x16x32_bf16(a[Mt], bw[kc&1][t], hacc[Mt][t], 0, 0, 0);
  }

  if (dosync) __syncthreads();   // prev expert's GEMM2 done reading Hs

  // epilogue: +b1, fast SiLU, scale by gathered gate weight, scatter to Hs
#pragma unroll
  for (int Mt = 0; Mt < MTC; ++Mt) {
    const int g0 = Mt*16 + q*4;
    const unsigned pw = *(const unsigned*)(plist_e + g0);   // 4 packed positions
    const f32x4 wg = *(const f32x4*)(wgtg_e + g0);
#pragma unroll
    for (int t = 0; t < 2; ++t) {
      const int n = wv*32 + t*16 + r;
      const float bias = b1e[n];
#pragma unroll
      for (int reg = 0; reg < 4; ++reg) {
        const int p = (pw >> (8*reg)) & 255;
        const float z = hacc[Mt][t][reg] + bias;
        const float s = __builtin_amdgcn_rcpf(1.0f + __expf(-z));
        HsS[p*XST + n] = bfq(z * s * wg[reg]);
      }
    }
  }
}

__global__ __launch_bounds__(512, 4) void moe_fused_kernel(
    const float* __restrict__ x,
    const float* __restrict__ gate_w,
    const float* __restrict__ gate_b,
    const float* __restrict__ b1,
    const float* __restrict__ b2,
    const __hip_bfloat16* __restrict__ wp,   // [W1P | W2P] prepacked bf16
    float* __restrict__ out)
{
  // pool (69632 B): phase 1 Xs (33792) + Hs (33792); epilogue O tile 256xOSTx4.
  // Gate fp64 partials (16KB) alias the Hs region before its first use.
  __shared__ __align__(16) char pool[256 * OST * 4];
  __shared__ __align__(16) float Wgt[MT * 4];
  __shared__ __align__(16) unsigned char plist[4][64];  // gathered positions
  __shared__ __align__(16) float WgtG[4][64];           // gathered gate weights
  __shared__ __align__(4)  unsigned char zlist[4][64];  // complement positions
  __shared__ int mcnt[4];

  short* XsS = (short*)pool;
  short* HsS = (short*)(pool + MT * XST * 2);
  float* Os  = (float*)pool;

  const int tid  = threadIdx.x;
  const int lane = tid & 63;
  const int wv   = tid >> 6;     // wave 0..7: owns n-slice [wv*32, wv*32+32)
  const int r    = lane & 15;
  const int q    = lane >> 4;

  const int g  = blockIdx.x;
  const int b  = g >> 8;                 // 256 workgroups per batch
  const int s0 = (g & 255) * MT;
  const float* xb = x + (size_t)b * C_DIM * S_DIM + s0;

  // ---- FUSED stage X + gate partials: wave wv owns channels [wv*32, wv*32+32),
  //      lane = position. 32 coalesced scalar loads; fp64 gate dot from regs. ----
  {
    const int p  = lane;
    const int c0 = wv * 32;
    float xv[32];
#pragma unroll
    for (int j = 0; j < 32; ++j)
      xv[j] = xb[(size_t)(c0 + j) * S_DIM + p];

    double acc[4] = {0.0, 0.0, 0.0, 0.0};
#pragma unroll
    for (int j = 0; j < 32; ++j) {
      const double xd = (double)xv[j];
      acc[0] += xd * (double)gate_w[0*256 + c0 + j];
      acc[1] += xd * (double)gate_w[1*256 + c0 + j];
      acc[2] += xd * (double)gate_w[2*256 + c0 + j];
      acc[3] += xd * (double)gate_w[3*256 + c0 + j];
    }

#pragma unroll
    for (int k = 0; k < 4; ++k) {
      bf16x8 blk = {bfq(xv[k*8+0]), bfq(xv[k*8+1]), bfq(xv[k*8+2]), bfq(xv[k*8+3]),
                    bfq(xv[k*8+4]), bfq(xv[k*8+5]), bfq(xv[k*8+6]), bfq(xv[k*8+7])};
      *(bf16x8*)(XsS + p*XST + c0 + k*8) = blk;
    }

    double* GateD = (double*)HsS;   // 64pos x 4e x 8grp fp64 = 16KB (alias)
#pragma unroll
    for (int e = 0; e < 4; ++e)
      GateD[(e*8 + wv)*64 + p] = acc[e];
  }
  __syncthreads();   // Xs staged AND gate partials written

  // ---- logits (fp64 reduce, fixed order) + top-2 + softmax, fused via shfl ----
  if (tid < 256) {
    const int p = tid >> 2;
    const int e = tid & 3;
    const double* GateD = (const double*)HsS;
    double s = (double)gate_b[e];
#pragma unroll
    for (int g2 = 0; g2 < 8; ++g2) s += GateD[(e*8 + g2)*64 + p];
    const float la = (float)s;              // l[e]
    const float lb = __shfl_xor(la, 1, 64); // l[e^1]
    const float lc = __shfl_xor(la, 2, 64); // l[e^2]
    const float ld = __shfl_xor(lb, 2, 64); // l[e^3]
    if (e == 0) {
      const float l0 = la, l1 = lb, l2 = lc, l3 = ld;
      int i1 = 0; float v1 = l0;
      if (l1 > v1) { v1 = l1; i1 = 1; }
      if (l2 > v1) { v1 = l2; i1 = 2; }
      if (l3 > v1) { v1 = l3; i1 = 3; }
      float v2 = -3.0e38f; int i2 = 0;
      if (i1 != 0 && l0 > v2) { v2 = l0; i2 = 0; }
      if (i1 != 1 && l1 > v2) { v2 = l1; i2 = 1; }
      if (i1 != 2 && l2 > v2) { v2 = l2; i2 = 2; }
      if (i1 != 3 && l3 > v2) { v2 = l3; i2 = 3; }
      const float wA = 1.0f / (1.0f + __expf(v2 - v1));
      const float wB = 1.0f - wA;
      f32x4 w;
      w[0] = (i1 == 0) ? wA : ((i2 == 0) ? wB : 0.0f);
      w[1] = (i1 == 1) ? wA : ((i2 == 1) ? wB : 0.0f);
      w[2] = (i1 == 2) ? wA : ((i2 == 2) ? wB : 0.0f);
      w[3] = (i1 == 3) ? wA : ((i2 == 3) ? wB : 0.0f);
      *(f32x4*)(&Wgt[p*4]) = w;
    }
  }
  __syncthreads();   // Wgt final

  // ---- per-expert gather lists via ballot (waves 0..3) ----
  if (wv < 4) {
    const int e = wv;
    const int p = lane;
    const float w = Wgt[p*4 + e];
    const bool sel = (w != 0.0f);
    const unsigned long long mask = __ballot(sel);
    const int below = __popcll(mask & ((1ull << p) - 1ull));
    const int m = __popcll(mask);
    const int pad = (((m + 15) >> 4) << 4) - m;
    if (sel) {
      plist[e][below] = (unsigned char)p;
      WgtG[e][below]  = w;
    } else {
      const int zidx = p - below;
      zlist[e][zidx] = (unsigned char)p;
      if (zidx < pad) {   // tail-tile padding: weight-0 complement rows
        plist[e][m + zidx] = (unsigned char)p;
        WgtG[e][m + zidx]  = 0.0f;
      }
    }
    if (p == 0) mcnt[e] = m;
  }
  __syncthreads();   // lists final (also: GateD fully consumed before H-scatter)

  const short* W1P = (const short*)wp;
  const short* W2P = (const short*)wp + WFRAG_ELEMS;

  f32x4 oacc[4][2];   // [Mt][t]: persistent out accumulator, K=1024 concat
#pragma unroll
  for (int i = 0; i < 4; ++i)
#pragma unroll
    for (int j = 0; j < 2; ++j) oacc[i][j] = (f32x4){0.f, 0.f, 0.f, 0.f};

  for (int e = 0; e < E_DIM; ++e) {
    const int me = mcnt[e];   // WG-uniform
    const int mt = __builtin_amdgcn_readfirstlane((me + 15) >> 4);
    const short* w1e = W1P + ((e*16 + wv*2)*8)*512 + lane*8;
    const float* b1e = b1 + e*256;
    const bool dosync = (e > 0);   // wait for prev GEMM2's Hs readers

    if      (mt == 2) gemm1_sparse<2>(XsS, HsS, w1e, b1e, plist[e], WgtG[e], wv, r, q, dosync);
    else if (mt == 3) gemm1_sparse<3>(XsS, HsS, w1e, b1e, plist[e], WgtG[e], wv, r, q, dosync);
    else if (mt == 4) gemm1_sparse<4>(XsS, HsS, w1e, b1e, plist[e], WgtG[e], wv, r, q, dosync);
    else if (mt == 1) gemm1_sparse<1>(XsS, HsS, w1e, b1e, plist[e], WgtG[e], wv, r, q, dosync);
    else { if (dosync) __syncthreads(); }   // mt==0: still must sync

    // prefetch GEMM2's first kc B-fragments
    const short* w2e = W2P + ((e*16 + wv*2)*8)*512 + lane*8;
    bf16x8 cw[2][2];
#pragma unroll
    for (int t = 0; t < 2; ++t) cw[0][t] = *(const bf16x8*)(w2e + (t*8 + 0)*512);

    // zero-fill complement rows of Hs (positions not using expert e)
    {
      const int zm = 64 - me;
      const bf16x8 zz = {0,0,0,0,0,0,0,0};
      for (int i = tid; i < zm*32; i += 512) {
        const int row = zlist[e][i >> 5];
        *(bf16x8*)(HsS + row*XST + (i & 31)*8) = zz;
      }
    }
    __syncthreads();   // Hs complete (gathered writes + zero fill)

    // ---- GEMM2: oacc += H_e(64x256) @ W2_e^T slice, ring-2 prefetch ----
    {
#pragma unroll
      for (int kc = 0; kc < 8; ++kc) {
        if (kc < 7) {
#pragma unroll
          for (int t = 0; t < 2; ++t)
            cw[(kc+1)&1][t] = *(const bf16x8*)(w2e + (t*8 + kc + 1)*512);
        }
        bf16x8 a[4];
#pragma unroll
        for (int Mt = 0; Mt < 4; ++Mt)
          a[Mt] = *(const bf16x8*)(HsS + (Mt*16 + r)*XST + kc*32 + q*8);
#pragma unroll
        for (int Mt = 0; Mt < 4; ++Mt)
#pragma unroll
          for (int t = 0; t < 2; ++t)
            oacc[Mt][t] = __builtin_amdgcn_mfma_f32_16x16x32_bf16(a[Mt], cw[kc&1][t], oacc[Mt][t], 0, 0, 0);
      }
    }
    // no barrier here: next expert's GEMM1 compute doesn't touch Hs; the
    // barrier protecting Hs sits inside gemm1_sparse, before its scatter.
  }
  __syncthreads();   // last GEMM2 done; pool may be reused as O tile

  // ---- O epilogue part 1: oacc + b2-wsum -> fp32 LDS O tile (b128 writes) ----
  {
    float b2v[2][4];   // [t][e] for c = wv*32 + t*16 + r
#pragma unroll
    for (int t = 0; t < 2; ++t) {
      const int c = wv*32 + t*16 + r;
#pragma unroll
      for (int e = 0; e < 4; ++e) b2v[t][e] = b2[e*256 + c];
    }
#pragma unroll
    for (int Mt = 0; Mt < 4; ++Mt) {
      f32x4 wv4[4];
#pragma unroll
      for (int reg = 0; reg < 4; ++reg)
        wv4[reg] = *(const f32x4*)(&Wgt[(Mt*16 + q*4 + reg)*4]);
#pragma unroll
      for (int t = 0; t < 2; ++t) {
        f32x4 v = oacc[Mt][t];
#pragma unroll
        for (int reg = 0; reg < 4; ++reg)
          v[reg] += wv4[reg][0]*b2v[t][0] + wv4[reg][1]*b2v[t][1]
                  + wv4[reg][2]*b2v[t][2] + wv4[reg][3]*b2v[t][3];
        *(f32x4*)(Os + (size_t)(wv*32 + t*16 + r)*OST + Mt*16 + q*4) = v;
      }
    }
  }
  __syncthreads();

  // ---- O epilogue part 2: coalesced residual-add + float4 store ----
  {
    const int p4 = (tid & 15) * 4;
    const int cg = tid >> 4;             // 0..31
    float* ob = out + (size_t)b * C_DIM * S_DIM + s0;
#pragma unroll
    for (int cc = 0; cc < 8; ++cc) {
      const int c = cc*32 + cg;
      const f32x4  o  = *(const f32x4*)(Os + (size_t)c*OST + p4);
      const float4 xr = *(const float4*)(xb + (size_t)c*S_DIM + p4);
      float4 res;
      res.x = o[0] + xr.x; res.y = o[1] + xr.y;
      res.z = o[2] + xr.z; res.w = o[3] + xr.w;
      *(float4*)(ob + (size_t)c*S_DIM + p4) = res;
    }
  }
}

extern "C" void kernel_launch(void* const* d_in, const int* in_sizes, int n_in,
                              void* d_out, int out_size, void* d_ws, size_t ws_size,
                              hipStream_t stream)
{
  (void)in_sizes; (void)n_in; (void)out_size; (void)ws_size;
  const float* x      = (const float*)d_in[0];
  const float* gate_w = (const float*)d_in[1];
  const float* gate_b = (const float*)d_in[2];
  const float* w1     = (const float*)d_in[3];
  const float* b1     = (const float*)d_in[4];
  const float* w2     = (const float*)d_in[5];
  const float* b2     = (const float*)d_in[6];
  float* out = (float*)d_out;
  __hip_bfloat16* wpack = (__hip_bfloat16*)d_ws;   // needs 1 MiB of scratch

  prepack_kernel<<<256, 256, 0, stream>>>(w1, w2, wpack);
  moe_fused_kernel<<<512, 512, 0, stream>>>(x, gate_w, gate_b, b1, b2, wpack, out);
}